// Round 4
// baseline (387.929 us; speedup 1.0000x reference)
//
#include <hip/hip_runtime.h>
#include <hip/hip_bf16.h>

#define BATCH 4096

typedef __attribute__((ext_vector_type(8))) short short8;
typedef __attribute__((ext_vector_type(16))) float f32x16;

// ---------------- d_ws layout (bf16 elems) ----------------
// wb1 @0 (512), wb2 @512 (4608), wb3 @5120 (18432), wb4 @23552 (73728)
#define WB1_ELEM 0
#define WB2_ELEM 512
#define WB3_ELEM 5120
#define WB4_ELEM 23552
#define WB_TOTAL 97280

// ---------------- LDS layout (byte offsets), 65232 B total ----------------
// sb  bf16 [34][34]      @0      (2312, pad 2320)
// a1  bf16 [34][34][16]  @2320   (36992)  XOR-swz key=((col>>2)&1)<<4
// a2  bf16 [18][18][40]  @39312  (25920)
// a3  bf16 [10][10][72]  @0      (14400)  XOR-swz key=(col&3)<<5  (reuses sb+a1)
// meanp f32 [2][128]     @14400  (1024)
// meanv f32 [128]        @15424  (512)
#define A1_OFF 2320
#define A2_OFF 39312
#define MEANP_OFF 14400
#define MEANV_OFF 15424
#define SMEM_BYTES 65232

static __device__ __forceinline__ unsigned pack2(float a, float b) {
    __hip_bfloat16 lo = __float2bfloat16(a), hi = __float2bfloat16(b);
    unsigned short ul = *(unsigned short*)&lo, uh = *(unsigned short*)&hi;
    return ((unsigned)uh << 16) | ul;
}

// ---------------------------------------------------------------------------
// Weight repack.
// wb1: [oc 32][k 16]  (oc>=16 or k>=9 -> 0), k = tap
// wb2/3/4: [oc][tap 9][ic] bf16, k-contiguous per tap
// ---------------------------------------------------------------------------
__global__ void prepack_weights(const float* __restrict__ w1,
                                const float* __restrict__ w2,
                                const float* __restrict__ w3,
                                const float* __restrict__ w4,
                                __hip_bfloat16* __restrict__ wb) {
    int g = blockIdx.x * 256 + threadIdx.x;
    if (g < 512) {
        int oc = g >> 4, k = g & 15;
        float v = (oc < 16 && k < 9) ? w1[oc * 9 + k] : 0.f;
        wb[g] = __float2bfloat16(v);
    } else if (g < WB3_ELEM) {
        int gg = g - WB2_ELEM;
        int oc = gg / 144, r = gg - oc * 144, tap = r >> 4, ic = r & 15;
        wb[g] = __float2bfloat16(w2[oc * 144 + ic * 9 + tap]);
    } else if (g < WB4_ELEM) {
        int gg = g - WB3_ELEM;
        int oc = gg / 288, r = gg - oc * 288, tap = r >> 5, ic = r & 31;
        wb[g] = __float2bfloat16(w3[oc * 288 + ic * 9 + tap]);
    } else if (g < WB_TOTAL) {
        int gg = g - WB4_ELEM;
        int oc = gg / 576, r = gg - oc * 576, tap = r >> 6, ic = r & 63;
        wb[g] = __float2bfloat16(w4[oc * 576 + ic * 9 + tap]);
    }
}

// ---------------------------------------------------------------------------
// Fully fused CNN: one block (512 thr, 8 waves) per image, 2 blocks/CU.
// ---------------------------------------------------------------------------
__global__ __launch_bounds__(512, 4) void cnn_fused_kernel(
    const float* __restrict__ board,
    const float* __restrict__ b1, const float* __restrict__ b2,
    const float* __restrict__ b3, const float* __restrict__ b4,
    const float* __restrict__ pw, const float* __restrict__ pb,
    const __hip_bfloat16* __restrict__ wb,
    float* __restrict__ bf_out)
{
    __shared__ alignas(16) char smem[SMEM_BYTES];
    unsigned short* sbu = (unsigned short*)smem;
    char* a1b = smem + A1_OFF;
    char* a2b = smem + A2_OFF;
    char* a3b = smem;
    float* meanp = (float*)(smem + MEANP_OFF);
    float* meanv = (float*)(smem + MEANV_OFF);

    const int t = threadIdx.x;
    const int img = blockIdx.x;
    const int w = t >> 6;          // wave 0..7
    const int l = t & 63;
    const int n = l & 31;
    const int h = l >> 5;

    // ---- P0: zero everything ----
    {
        uint4 z; z.x = z.y = z.z = z.w = 0u;
        for (int i = t; i < SMEM_BYTES / 16; i += 512) ((uint4*)smem)[i] = z;
    }
    __syncthreads();

    // ---- P1: load board (f32 -> bf16, padded interior) ----
    {
        float2 v = ((const float2*)board)[img * 512 + t];
        const int p = t * 2;
        const int row = (p >> 5) + 1, col = (p & 31) + 1;
        unsigned short* d = sbu + row * 34 + col;
        __hip_bfloat16 x0 = __float2bfloat16(v.x), x1 = __float2bfloat16(v.y);
        d[0] = *(unsigned short*)&x0;
        d[1] = *(unsigned short*)&x1;
    }
    __syncthreads();

    // ---- P2: conv1 (MFMA, taps as K): 1->16, relu -> a1 (swizzled) ----
    {
        const short8 A1 = *(const short8*)((const char*)wb + (n * 16 + h * 8) * 2);
        float b1s[8];
#pragma unroll
        for (int r = 0; r < 8; ++r) b1s[r] = b1[(r & 3) + 8 * (r >> 2) + 4 * h];
        const unsigned* sbw = (const unsigned*)smem;
#pragma unroll 1
        for (int yi = 0; yi < 4; ++yi) {
            const int y = 4 * w + yi;
            unsigned short c[3][3];
#pragma unroll
            for (int dy = 0; dy < 3; ++dy) {
                const int base = (y + dy) * 17 + (n >> 1);
                const unsigned w0 = sbw[base], w1 = sbw[base + 1];
                if (n & 1) {
                    c[dy][0] = (unsigned short)(w0 >> 16);
                    c[dy][1] = (unsigned short)(w1 & 0xffff);
                    c[dy][2] = (unsigned short)(w1 >> 16);
                } else {
                    c[dy][0] = (unsigned short)(w0 & 0xffff);
                    c[dy][1] = (unsigned short)(w0 >> 16);
                    c[dy][2] = (unsigned short)(w1 & 0xffff);
                }
            }
            short8 Bv;
            if (h == 0) {
                Bv[0] = (short)c[0][0]; Bv[1] = (short)c[0][1]; Bv[2] = (short)c[0][2];
                Bv[3] = (short)c[1][0]; Bv[4] = (short)c[1][1]; Bv[5] = (short)c[1][2];
                Bv[6] = (short)c[2][0]; Bv[7] = (short)c[2][1];
            } else {
                Bv = (short8)0;
                Bv[0] = (short)c[2][2];
            }
            f32x16 acc = __builtin_amdgcn_mfma_f32_32x32x16_bf16(A1, Bv, (f32x16)0.0f, 0, 0, 0);
            float v8[8];
#pragma unroll
            for (int r = 0; r < 8; ++r) v8[r] = fmaxf(acc[r] + b1s[r], 0.f);
            const int col = n + 1;
            const int key = ((col >> 2) & 1) << 4;
            char* dst = a1b + ((y + 1) * 34 + col) * 32;
            uint2 u0, u1;
            u0.x = pack2(v8[0], v8[1]); u0.y = pack2(v8[2], v8[3]);
            u1.x = pack2(v8[4], v8[5]); u1.y = pack2(v8[6], v8[7]);
            *(uint2*)(dst + ((h * 8) ^ key)) = u0;
            *(uint2*)(dst + ((h * 8 + 16) ^ key)) = u1;
        }
    }
    __syncthreads();

    // ---- P3: conv2 (MFMA): 16->32, relu + 2x2 maxpool -> a2 ----
    {
        const char* wb2 = (const char*)(wb + WB2_ELEM);
        short8 A[9];
#pragma unroll
        for (int tp = 0; tp < 9; ++tp)
            A[tp] = *(const short8*)(wb2 + (n * 144 + tp * 16 + h * 8) * 2);
        float bias[16];
#pragma unroll
        for (int r = 0; r < 16; ++r) bias[r] = b2[(r & 3) + 8 * (r >> 2) + 4 * h];

#pragma unroll 1
        for (int pr = 0; pr < 2; ++pr) {
            const int y0 = 4 * w + 2 * pr;
            f32x16 accA = (f32x16)0.0f, accB = (f32x16)0.0f;
#pragma unroll
            for (int rr = 0; rr < 4; ++rr) {
                short8 B[3];
#pragma unroll
                for (int dx = 0; dx < 3; ++dx) {
                    const int cc = n + dx;
                    const int key = ((cc >> 2) & 1) << 4;
                    B[dx] = *(const short8*)(a1b + ((y0 + rr) * 34 + cc) * 32 + ((h * 16) ^ key));
                }
                if (rr < 3) {
#pragma unroll
                    for (int dx = 0; dx < 3; ++dx)
                        accA = __builtin_amdgcn_mfma_f32_32x32x16_bf16(A[rr * 3 + dx], B[dx], accA, 0, 0, 0);
                }
                if (rr > 0) {
#pragma unroll
                    for (int dx = 0; dx < 3; ++dx)
                        accB = __builtin_amdgcn_mfma_f32_32x32x16_bf16(A[(rr - 1) * 3 + dx], B[dx], accB, 0, 0, 0);
                }
            }
            float v[16];
#pragma unroll
            for (int r = 0; r < 16; ++r) {
                float m = fmaxf(accA[r], accB[r]);
                m = fmaxf(m, __shfl_xor(m, 1));
                v[r] = fmaxf(m + bias[r], 0.f);
            }
            const int py = 2 * w + pr, px = n >> 1;
            const int qb = (n & 1) * 2;
            char* dst = a2b + ((py + 1) * 18 + (px + 1)) * 80;
#pragma unroll
            for (int qq = 0; qq < 2; ++qq) {
                const int q = qb + qq;
                uint2 u;
                u.x = pack2(v[4 * q + 0], v[4 * q + 1]);
                u.y = pack2(v[4 * q + 2], v[4 * q + 3]);
                *(uint2*)(dst + (8 * q + 4 * h) * 2) = u;
            }
        }
    }
    __syncthreads();

    // ---- P4: zero a3 + meanp + meanv region (sb/a1 are dead) ----
    {
        uint4 z; z.x = z.y = z.z = z.w = 0u;
        for (int i = t; i < 15936 / 16; i += 512) ((uint4*)smem)[i] = z;
    }
    __syncthreads();

    // ---- P5: conv3 (MFMA): 32->64, relu+pool -> a3 (swizzled), 2 chains ----
    {
        const char* wb3 = (const char*)(wb + WB3_ELEM);
        const int mt = w >> 2;                 // oc tile 0..1
        const int np = w & 3;
        const int nt0 = 2 * np, nt1 = 2 * np + 1;
        float bias[16];
#pragma unroll
        for (int r = 0; r < 16; ++r) bias[r] = b3[32 * mt + (r & 3) + 8 * (r >> 2) + 4 * h];

        const int x = n & 15;
        const int base0 = ((2 * nt0 + (n >> 4)) * 18 + x) * 80 + h * 16;
        const int base1 = ((2 * nt1 + (n >> 4)) * 18 + x) * 80 + h * 16;
        f32x16 acc0 = (f32x16)0.0f, acc1 = (f32x16)0.0f;
#pragma unroll 1
        for (int half = 0; half < 2; ++half) {
            short8 A[9];
#pragma unroll
            for (int j = 0; j < 9; ++j) {
                const int ks = 9 * half + j, tp = ks >> 1, kh = ks & 1;
                A[j] = *(const short8*)(wb3 + ((mt * 32 + n) * 288 + tp * 32 + kh * 16 + h * 8) * 2);
            }
#pragma unroll
            for (int j = 0; j < 9; ++j) {
                const int ks = 9 * half + j, tp = ks >> 1, kh = ks & 1;
                const int dy = tp / 3, dx = tp - 3 * dy;
                const int off = dy * 1440 + dx * 80 + kh * 32;
                short8 B0 = *(const short8*)(a2b + base0 + off);
                short8 B1 = *(const short8*)(a2b + base1 + off);
                acc0 = __builtin_amdgcn_mfma_f32_32x32x16_bf16(A[j], B0, acc0, 0, 0, 0);
                acc1 = __builtin_amdgcn_mfma_f32_32x32x16_bf16(A[j], B1, acc1, 0, 0, 0);
            }
        }
#pragma unroll
        for (int e = 0; e < 2; ++e) {
            const f32x16 acc = e ? acc1 : acc0;
            const int nt = e ? nt1 : nt0;
            float v[16];
#pragma unroll
            for (int r = 0; r < 16; ++r) {
                float m = fmaxf(acc[r], __shfl_xor(acc[r], 16));
                m = fmaxf(m, __shfl_xor(m, 1));
                v[r] = fmaxf(m + bias[r], 0.f);
            }
            if (n < 16) {
                const int pc = ((n & 15) >> 1) + 1;
                const int key = (pc & 3) << 5;
                char* pixb = a3b + ((nt + 1) * 10 + pc) * 144;
                const int qb = (n & 1) * 2;
#pragma unroll
                for (int qq = 0; qq < 2; ++qq) {
                    const int q = qb + qq;
                    uint2 u;
                    u.x = pack2(v[4 * q + 0], v[4 * q + 1]);
                    u.y = pack2(v[4 * q + 2], v[4 * q + 3]);
                    *(uint2*)(pixb + ((64 * mt + 16 * q + 8 * h) ^ key)) = u;
                }
            }
        }
    }
    __syncthreads();

    // ---- P6: conv4 (MFMA): 64->128, relu + partial avg -> meanp, 2 chains ----
    {
        const char* wb4 = (const char*)(wb + WB4_ELEM);
        const int mt = w >> 1, half = w & 1;
        float bias[16];
#pragma unroll
        for (int r = 0; r < 16; ++r) bias[r] = b4[32 * mt + (r & 3) + 8 * (r >> 2) + 4 * h];
        const int x = n & 7, yq = (n >> 3) + 4 * half;
        f32x16 acc_e = (f32x16)0.0f, acc_o = (f32x16)0.0f;
#pragma unroll
        for (int dy = 0; dy < 3; ++dy)
#pragma unroll
            for (int dx = 0; dx < 3; ++dx) {
                const int pc = x + dx;
                const int key = (pc & 3) << 5;
                const char* p0 = a3b + ((yq + dy) * 10 + pc) * 144 + h * 16;
#pragma unroll
                for (int ks = 0; ks < 4; ++ks) {
                    short8 A = *(const short8*)(wb4 + ((32 * mt + n) * 576 + (dy * 3 + dx) * 64 + ks * 16 + h * 8) * 2);
                    short8 B = *(const short8*)(p0 + ((ks * 32) ^ key));
                    if (ks & 1) acc_o = __builtin_amdgcn_mfma_f32_32x32x16_bf16(A, B, acc_o, 0, 0, 0);
                    else        acc_e = __builtin_amdgcn_mfma_f32_32x32x16_bf16(A, B, acc_e, 0, 0, 0);
                }
            }
        float s[16];
#pragma unroll
        for (int r = 0; r < 16; ++r)
            s[r] = fmaxf(acc_e[r] + acc_o[r] + bias[r], 0.f);
#pragma unroll
        for (int r = 0; r < 16; ++r) {
            float x2 = s[r];
            x2 += __shfl_xor(x2, 1);
            x2 += __shfl_xor(x2, 2);
            x2 += __shfl_xor(x2, 4);
            x2 += __shfl_xor(x2, 8);
            x2 += __shfl_xor(x2, 16);
            s[r] = x2;
        }
        if (n == 0) {
#pragma unroll
            for (int r = 0; r < 16; ++r)
                meanp[half * 128 + 32 * mt + (r & 3) + 8 * (r >> 2) + 4 * h] = s[r];
        }
    }
    __syncthreads();

    // ---- P7: combine halves -> meanv ----
    if (t < 128) meanv[t] = (meanp[t] + meanp[128 + t]) * (1.f / 64.f);
    __syncthreads();

    // ---- P8: proj ----
    if (t < 256) {
        const int o = t >> 1, kh = t & 1;
        const float* wrow = pw + o * 128 + kh * 64;
        const float* mv = meanv + kh * 64;
        float acc = 0.f;
        for (int k = 0; k < 64; ++k) acc = fmaf(mv[k], wrow[k], acc);
        acc += __shfl_xor(acc, 1);
        if (kh == 0) bf_out[img * 128 + o] = acc + pb[o];
    }
}

// ---------------------------------------------------------------------------
// Kernel C: GRU step + head (unchanged).
// ---------------------------------------------------------------------------
__global__ __launch_bounds__(384) void gru_kernel(
    const float* __restrict__ hin,
    const int* __restrict__ atok, const int* __restrict__ uidx,
    const float* __restrict__ emb,
    const float* __restrict__ w_ih, const float* __restrict__ w_hh,
    const float* __restrict__ b_ih, const float* __restrict__ b_hh,
    const float* __restrict__ head_w, const float* __restrict__ head_b,
    float* __restrict__ out)
{
    const int img0 = blockIdx.x * 8;
    const int t = threadIdx.x;
    __shared__ float xin_s[8][168];
    __shared__ float h0_s[8][128];
    __shared__ float gis[8][384];
    __shared__ float ghs[8][384];
    __shared__ float hn_s[8][128];
    const float* bf = out + BATCH * 6;

    for (int idx = t; idx < 8 * 168; idx += 384) {
        const int r = idx / 168, k = idx - r * 168;
        const int row = img0 + r;
        float v;
        if (k < 128)      v = bf[row * 128 + k];
        else if (k < 136) v = (float)((atok[row] >> (k - 128)) & 1);
        else              v = emb[uidx[row] * 32 + (k - 136)];
        xin_s[r][k] = v;
    }
    for (int idx = t; idx < 8 * 128; idx += 384) {
        const int r = idx >> 7, k = idx & 127;
        h0_s[r][k] = hin[(img0 + r) * 128 + k];
    }
    __syncthreads();

    {
        const int o = t;
        float gi[8], gh[8];
        const float bi = b_ih[o], bh = b_hh[o];
#pragma unroll
        for (int r = 0; r < 8; ++r) { gi[r] = bi; gh[r] = bh; }
        const float* wi = w_ih + o * 168;
        const float* wh = w_hh + o * 128;
        for (int k = 0; k < 128; ++k) {
            const float wv = wi[k];
            const float wvh = wh[k];
#pragma unroll
            for (int r = 0; r < 8; ++r) {
                gi[r] = fmaf(wv, xin_s[r][k], gi[r]);
                gh[r] = fmaf(wvh, h0_s[r][k], gh[r]);
            }
        }
        for (int k = 128; k < 168; ++k) {
            const float wv = wi[k];
#pragma unroll
            for (int r = 0; r < 8; ++r) gi[r] = fmaf(wv, xin_s[r][k], gi[r]);
        }
#pragma unroll
        for (int r = 0; r < 8; ++r) { gis[r][o] = gi[r]; ghs[r][o] = gh[r]; }
    }
    __syncthreads();

    if (t < 128) {
#pragma unroll
        for (int r = 0; r < 8; ++r) {
            const float rg = 1.f / (1.f + expf(-(gis[r][t] + ghs[r][t])));
            const float z  = 1.f / (1.f + expf(-(gis[r][128 + t] + ghs[r][128 + t])));
            const float nn = tanhf(gis[r][256 + t] + rg * ghs[r][256 + t]);
            const float hn = (1.f - z) * nn + z * h0_s[r][t];
            hn_s[r][t] = hn;
            out[BATCH * 6 + (img0 + r) * 128 + t] = hn;
        }
    }
    __syncthreads();

    if (t < 48) {
        const int r = t / 6, j = t - r * 6;
        float acc = head_b[j];
        const float* wrow = head_w + j * 128;
        for (int k = 0; k < 128; ++k) acc = fmaf(hn_s[r][k], wrow[k], acc);
        out[(img0 + r) * 6 + j] = acc;
    }
}

extern "C" void kernel_launch(void* const* d_in, const int* in_sizes, int n_in,
                              void* d_out, int out_size, void* d_ws, size_t ws_size,
                              hipStream_t stream) {
    const float* board = (const float*)d_in[0];
    const float* h     = (const float*)d_in[1];
    const int*   atok  = (const int*)d_in[2];
    const int*   uidx  = (const int*)d_in[3];
    const float* w1 = (const float*)d_in[4];
    const float* b1 = (const float*)d_in[5];
    const float* w2 = (const float*)d_in[6];
    const float* b2 = (const float*)d_in[7];
    const float* w3 = (const float*)d_in[8];
    const float* b3 = (const float*)d_in[9];
    const float* w4 = (const float*)d_in[10];
    const float* b4 = (const float*)d_in[11];
    const float* pw = (const float*)d_in[12];
    const float* pb = (const float*)d_in[13];
    const float* emb  = (const float*)d_in[14];
    const float* w_ih = (const float*)d_in[15];
    const float* w_hh = (const float*)d_in[16];
    const float* b_ih = (const float*)d_in[17];
    const float* b_hh = (const float*)d_in[18];
    const float* head_w = (const float*)d_in[19];
    const float* head_b = (const float*)d_in[20];
    float* out = (float*)d_out;
    __hip_bfloat16* wb = (__hip_bfloat16*)d_ws;

    float* bf = out + BATCH * 6;
    prepack_weights<<<(WB_TOTAL + 255) / 256, 256, 0, stream>>>(w1, w2, w3, w4, wb);
    cnn_fused_kernel<<<BATCH, 512, 0, stream>>>(board, b1, b2, b3, b4,
                                                pw, pb, wb, bf);
    gru_kernel<<<BATCH / 8, 384, 0, stream>>>(h, atok, uidx, emb, w_ih, w_hh,
                                              b_ih, b_hh, head_w, head_b, out);
}

// Round 5
// 278.702 us; speedup vs baseline: 1.3919x; 1.3919x over previous
//
#include <hip/hip_runtime.h>
#include <hip/hip_bf16.h>

#define BATCH 4096

typedef __attribute__((ext_vector_type(8))) short short8;
typedef __attribute__((ext_vector_type(16))) float f32x16;

// ---------------- d_ws layout ----------------
// a2g: bf16 [4096][16][16][32]  (pooled conv2, channel-last)  67,108,864 B
// wb:  bf16 weights after that: wb1 @0 (512), wb2 @512 (4608),
//      wb3 @5120 (18432), wb4 @23552 (73728)  -> 97280 elems
#define A2G_BYTES 67108864
#define WB1_ELEM 0
#define WB2_ELEM 512
#define WB3_ELEM 5120
#define WB4_ELEM 23552
#define WB_TOTAL 97280

static __device__ __forceinline__ unsigned pack2(float a, float b) {
    __hip_bfloat16 lo = __float2bfloat16(a), hi = __float2bfloat16(b);
    unsigned short ul = *(unsigned short*)&lo, uh = *(unsigned short*)&hi;
    return ((unsigned)uh << 16) | ul;
}

// ---------------------------------------------------------------------------
// Weight repack.
// wb1: [oc 32][k 16]  (oc>=16 or k>=9 -> 0), k = tap
// wb2/3/4: [oc][tap 9][ic] bf16, k-contiguous per tap
// ---------------------------------------------------------------------------
__global__ void prepack_weights(const float* __restrict__ w1,
                                const float* __restrict__ w2,
                                const float* __restrict__ w3,
                                const float* __restrict__ w4,
                                __hip_bfloat16* __restrict__ wb) {
    int g = blockIdx.x * 256 + threadIdx.x;
    if (g < 512) {
        int oc = g >> 4, k = g & 15;
        float v = (oc < 16 && k < 9) ? w1[oc * 9 + k] : 0.f;
        wb[g] = __float2bfloat16(v);
    } else if (g < WB3_ELEM) {
        int gg = g - WB2_ELEM;
        int oc = gg / 144, r = gg - oc * 144, tap = r >> 4, ic = r & 15;
        wb[g] = __float2bfloat16(w2[oc * 144 + ic * 9 + tap]);
    } else if (g < WB4_ELEM) {
        int gg = g - WB3_ELEM;
        int oc = gg / 288, r = gg - oc * 288, tap = r >> 5, ic = r & 31;
        wb[g] = __float2bfloat16(w3[oc * 288 + ic * 9 + tap]);
    } else if (g < WB_TOTAL) {
        int gg = g - WB4_ELEM;
        int oc = gg / 576, r = gg - oc * 576, tap = r >> 6, ic = r & 63;
        wb[g] = __float2bfloat16(w4[oc * 576 + ic * 9 + tap]);
    }
}

// ---------------------------------------------------------------------------
// Kernel A: conv1 (MFMA, taps as K) + conv2 (MFMA, rolling-B 2-chain) -> a2g.
// LDS: sb bf16 [34][34] @0 (2312, pad 2320) + a1 bf16 [34][34][16] @2320
//      (XOR-swz key=((col>>2)&1)<<4), total 39312 B.
// ---------------------------------------------------------------------------
__global__ __launch_bounds__(256, 3) void cnn12_kernel(
    const float* __restrict__ board,
    const float* __restrict__ b1, const float* __restrict__ b2,
    const __hip_bfloat16* __restrict__ wb,
    __hip_bfloat16* __restrict__ a2g)
{
    __shared__ alignas(16) char smem[39312];
    unsigned short* sbu = (unsigned short*)smem;     // bf16 board [34][34]
    char* a1b = smem + 2320;                         // bf16 [34][34][16] swz

    const int t = threadIdx.x;
    const int img = blockIdx.x;
    const int w = t >> 6;
    const int l = t & 63;
    const int n = l & 31;
    const int h = l >> 5;

    // ---- zero sbb + a1 ----
    {
        uint4 z; z.x = z.y = z.z = z.w = 0u;
        for (int i = t; i < 39312 / 16; i += 256) ((uint4*)smem)[i] = z;
    }
    __syncthreads();

    // ---- load board (f32 -> bf16, padded interior) ----
    {
        float4 v = ((const float4*)board)[img * 256 + t];
        const int p0 = t * 4;
        const int row = (p0 >> 5) + 1, col = (p0 & 31) + 1;
        unsigned short* d = sbu + row * 34 + col;
        __hip_bfloat16 x0 = __float2bfloat16(v.x), x1 = __float2bfloat16(v.y);
        __hip_bfloat16 x2 = __float2bfloat16(v.z), x3 = __float2bfloat16(v.w);
        d[0] = *(unsigned short*)&x0; d[1] = *(unsigned short*)&x1;
        d[2] = *(unsigned short*)&x2; d[3] = *(unsigned short*)&x3;
    }
    __syncthreads();

    // ---- conv1 (MFMA, taps as K): 1->16, relu -> a1 (swizzled) ----
    {
        const short8 A1 = *(const short8*)((const char*)wb + (n * 16 + h * 8) * 2);
        float b1s[8];
#pragma unroll
        for (int r = 0; r < 8; ++r) b1s[r] = b1[(r & 3) + 8 * (r >> 2) + 4 * h];
        const unsigned* sbw = (const unsigned*)smem;
#pragma unroll 1
        for (int yi = 0; yi < 8; ++yi) {
            const int y = 8 * w + yi;
            unsigned short c[3][3];
#pragma unroll
            for (int dy = 0; dy < 3; ++dy) {
                const int base = (y + dy) * 17 + (n >> 1);
                const unsigned w0 = sbw[base], w1v = sbw[base + 1];
                if (n & 1) {
                    c[dy][0] = (unsigned short)(w0 >> 16);
                    c[dy][1] = (unsigned short)(w1v & 0xffff);
                    c[dy][2] = (unsigned short)(w1v >> 16);
                } else {
                    c[dy][0] = (unsigned short)(w0 & 0xffff);
                    c[dy][1] = (unsigned short)(w0 >> 16);
                    c[dy][2] = (unsigned short)(w1v & 0xffff);
                }
            }
            short8 Bv;
            if (h == 0) {
                Bv[0] = (short)c[0][0]; Bv[1] = (short)c[0][1]; Bv[2] = (short)c[0][2];
                Bv[3] = (short)c[1][0]; Bv[4] = (short)c[1][1]; Bv[5] = (short)c[1][2];
                Bv[6] = (short)c[2][0]; Bv[7] = (short)c[2][1];
            } else {
                Bv = (short8)0;
                Bv[0] = (short)c[2][2];
            }
            f32x16 acc = __builtin_amdgcn_mfma_f32_32x32x16_bf16(A1, Bv, (f32x16)0.0f, 0, 0, 0);
            float v8[8];
#pragma unroll
            for (int r = 0; r < 8; ++r) v8[r] = fmaxf(acc[r] + b1s[r], 0.f);
            const int col = n + 1;
            const int key = ((col >> 2) & 1) << 4;
            char* dst = a1b + ((y + 1) * 34 + col) * 32;
            uint2 u0, u1;
            u0.x = pack2(v8[0], v8[1]); u0.y = pack2(v8[2], v8[3]);
            u1.x = pack2(v8[4], v8[5]); u1.y = pack2(v8[6], v8[7]);
            *(uint2*)(dst + ((h * 8) ^ key)) = u0;
            *(uint2*)(dst + ((h * 8 + 16) ^ key)) = u1;
        }
    }
    __syncthreads();

    // ---- conv2 (MFMA): 16->32, relu + 2x2 maxpool -> a2g, rolling-B ----
    {
        const char* wb2 = (const char*)(wb + WB2_ELEM);
        short8 A[9];
#pragma unroll
        for (int tp = 0; tp < 9; ++tp)
            A[tp] = *(const short8*)(wb2 + (n * 144 + tp * 16 + h * 8) * 2);
        float bias[16];
#pragma unroll
        for (int r = 0; r < 16; ++r) bias[r] = b2[(r & 3) + 8 * (r >> 2) + 4 * h];

#pragma unroll 1
        for (int pr = 0; pr < 4; ++pr) {
            const int y0 = 8 * w + 2 * pr;
            f32x16 accA = (f32x16)0.0f, accB = (f32x16)0.0f;
#pragma unroll
            for (int rr = 0; rr < 4; ++rr) {
                short8 B[3];
#pragma unroll
                for (int dx = 0; dx < 3; ++dx) {
                    const int cc = n + dx;
                    const int key = ((cc >> 2) & 1) << 4;
                    B[dx] = *(const short8*)(a1b + ((y0 + rr) * 34 + cc) * 32 + ((h * 16) ^ key));
                }
                if (rr < 3) {
#pragma unroll
                    for (int dx = 0; dx < 3; ++dx)
                        accA = __builtin_amdgcn_mfma_f32_32x32x16_bf16(A[rr * 3 + dx], B[dx], accA, 0, 0, 0);
                }
                if (rr > 0) {
#pragma unroll
                    for (int dx = 0; dx < 3; ++dx)
                        accB = __builtin_amdgcn_mfma_f32_32x32x16_bf16(A[(rr - 1) * 3 + dx], B[dx], accB, 0, 0, 0);
                }
            }
            float v[16];
#pragma unroll
            for (int r = 0; r < 16; ++r) {
                float m = fmaxf(accA[r], accB[r]);
                m = fmaxf(m, __shfl_xor(m, 1));
                v[r] = fmaxf(m + bias[r], 0.f);
            }
            const int py = 4 * w + pr, px = n >> 1;
            const int qb = (n & 1) * 2;
            __hip_bfloat16* gdst = a2g + (size_t)img * 8192 + (py * 16 + px) * 32;
#pragma unroll
            for (int qq = 0; qq < 2; ++qq) {
                const int q = qb + qq;
                uint2 u;
                u.x = pack2(v[4 * q + 0], v[4 * q + 1]);
                u.y = pack2(v[4 * q + 2], v[4 * q + 3]);
                *(uint2*)(gdst + 8 * q + 4 * h) = u;
            }
        }
    }
}

// ---------------------------------------------------------------------------
// Kernel B: conv3 (MFMA, 2-chain pairs) + conv4 (MFMA, swz a3) + avg + proj.
// LDS: a2 [18][18][40] @0 (25920) + a3 [10][10][72] @25920 (14400, XOR-swz)
//      + meanv f32[128] @40320 -> 40832 B.
// ---------------------------------------------------------------------------
__global__ __launch_bounds__(256, 3) void cnn34_kernel(
    const __hip_bfloat16* __restrict__ a2g,
    const float* __restrict__ b3, const float* __restrict__ b4,
    const float* __restrict__ pw, const float* __restrict__ pb,
    const __hip_bfloat16* __restrict__ wb,
    float* __restrict__ bf_out)
{
    __shared__ alignas(16) char smem[40832];
    char* a2b = smem;
    char* a3b = smem + 25920;
    float* meanv = (float*)(smem + 40320);

    const int t = threadIdx.x;
    const int img = blockIdx.x;
    const int w = t >> 6;
    const int l = t & 63;
    const int n = l & 31;
    const int h = l >> 5;

    const char* wb3 = (const char*)(wb + WB3_ELEM);
    const char* wb4 = (const char*)(wb + WB4_ELEM);

    // ---- zero all (borders + pad + meanv) ----
    {
        uint4 z; z.x = z.y = z.z = z.w = 0u;
        for (int i = t; i < 40832 / 16; i += 256) ((uint4*)smem)[i] = z;
    }
    __syncthreads();

    // ---- load a2 interior from global ----
    for (int i = t; i < 1024; i += 256) {
        const int p = i >> 2, c4 = i & 3;        // pixel, 16B-chunk
        const int py = p >> 4, px = p & 15;
        uint4 v = *(const uint4*)(a2g + (size_t)img * 8192 + p * 32 + c4 * 8);
        *(uint4*)(a2b + ((py + 1) * 18 + (px + 1)) * 80 + c4 * 16) = v;
    }
    __syncthreads();

    // ---- conv3 (MFMA): 32->64, relu+pool -> a3 (swizzled), 2-chain pairs ----
    {
        const int mt = w >> 1;                   // oc tile 0..1
        const int np = w & 1;
        float bias[16];
#pragma unroll
        for (int r = 0; r < 16; ++r) bias[r] = b3[32 * mt + (r & 3) + 8 * (r >> 2) + 4 * h];

#pragma unroll 1
        for (int p = 0; p < 2; ++p) {
            const int nt0 = 4 * np + 2 * p, nt1 = nt0 + 1;
            const int x = n & 15;
            const int base0 = ((2 * nt0 + (n >> 4)) * 18 + x) * 80 + h * 16;
            const int base1 = ((2 * nt1 + (n >> 4)) * 18 + x) * 80 + h * 16;
            f32x16 acc0 = (f32x16)0.0f, acc1 = (f32x16)0.0f;
#pragma unroll 1
            for (int half = 0; half < 2; ++half) {
                short8 A[9];
#pragma unroll
                for (int j = 0; j < 9; ++j) {
                    const int ks = 9 * half + j, tp = ks >> 1, kh = ks & 1;
                    A[j] = *(const short8*)(wb3 + ((mt * 32 + n) * 288 + tp * 32 + kh * 16 + h * 8) * 2);
                }
#pragma unroll
                for (int j = 0; j < 9; ++j) {
                    const int ks = 9 * half + j, tp = ks >> 1, kh = ks & 1;
                    const int dy = tp / 3, dx = tp - 3 * dy;
                    const int off = dy * 1440 + dx * 80 + kh * 32;
                    short8 B0 = *(const short8*)(a2b + base0 + off);
                    short8 B1 = *(const short8*)(a2b + base1 + off);
                    acc0 = __builtin_amdgcn_mfma_f32_32x32x16_bf16(A[j], B0, acc0, 0, 0, 0);
                    acc1 = __builtin_amdgcn_mfma_f32_32x32x16_bf16(A[j], B1, acc1, 0, 0, 0);
                }
            }
#pragma unroll
            for (int e = 0; e < 2; ++e) {
                const f32x16 acc = e ? acc1 : acc0;
                const int nt = e ? nt1 : nt0;
                float v[16];
#pragma unroll
                for (int r = 0; r < 16; ++r) {
                    float m = fmaxf(acc[r], __shfl_xor(acc[r], 16));
                    m = fmaxf(m, __shfl_xor(m, 1));
                    v[r] = fmaxf(m + bias[r], 0.f);
                }
                if (n < 16) {
                    const int pc = ((n & 15) >> 1) + 1;
                    const int key = (pc & 3) << 5;
                    char* pixb = a3b + ((nt + 1) * 10 + pc) * 144;
                    const int qb = (n & 1) * 2;
#pragma unroll
                    for (int qq = 0; qq < 2; ++qq) {
                        const int q = qb + qq;
                        uint2 u;
                        u.x = pack2(v[4 * q + 0], v[4 * q + 1]);
                        u.y = pack2(v[4 * q + 2], v[4 * q + 3]);
                        *(uint2*)(pixb + ((64 * mt + 16 * q + 8 * h) ^ key)) = u;
                    }
                }
            }
        }
    }
    __syncthreads();

    // ---- conv4 (MFMA): 64->128, relu + global avg -> meanv ----
    {
        const int mt = w;
        float bias[16];
#pragma unroll
        for (int r = 0; r < 16; ++r) bias[r] = b4[32 * mt + (r & 3) + 8 * (r >> 2) + 4 * h];
        const int x = n & 7, yq = n >> 3;
        f32x16 acc0 = (f32x16)0.0f, acc1 = (f32x16)0.0f;
#pragma unroll
        for (int dy = 0; dy < 3; ++dy)
#pragma unroll
            for (int dx = 0; dx < 3; ++dx) {
                const int pc = x + dx;                     // padded col 0..9
                const int key = (pc & 3) << 5;
                const char* p0 = a3b + ((yq + dy) * 10 + pc) * 144 + h * 16;
                const char* p1 = a3b + ((yq + 4 + dy) * 10 + pc) * 144 + h * 16;
#pragma unroll
                for (int ks = 0; ks < 4; ++ks) {
                    const int off = (ks * 32) ^ key;
                    short8 A = *(const short8*)(wb4 + ((32 * mt + n) * 576 + (dy * 3 + dx) * 64 + ks * 16 + h * 8) * 2);
                    short8 B0 = *(const short8*)(p0 + off);
                    short8 B1 = *(const short8*)(p1 + off);
                    acc0 = __builtin_amdgcn_mfma_f32_32x32x16_bf16(A, B0, acc0, 0, 0, 0);
                    acc1 = __builtin_amdgcn_mfma_f32_32x32x16_bf16(A, B1, acc1, 0, 0, 0);
                }
            }
        float s[16];
#pragma unroll
        for (int r = 0; r < 16; ++r)
            s[r] = fmaxf(acc0[r] + bias[r], 0.f) + fmaxf(acc1[r] + bias[r], 0.f);
#pragma unroll
        for (int r = 0; r < 16; ++r) {
            float x2 = s[r];
            x2 += __shfl_xor(x2, 1);
            x2 += __shfl_xor(x2, 2);
            x2 += __shfl_xor(x2, 4);
            x2 += __shfl_xor(x2, 8);
            x2 += __shfl_xor(x2, 16);
            s[r] = x2;
        }
        if (n == 0) {
#pragma unroll
            for (int r = 0; r < 16; ++r)
                meanv[32 * mt + (r & 3) + 8 * (r >> 2) + 4 * h] = s[r] * (1.f / 64.f);
        }
    }
    __syncthreads();

    // ---- proj (VALU) ----
    if (t < 128) {
        float acc = pb[t];
        const float* wrow = pw + t * 128;
        for (int k = 0; k < 128; ++k) acc = fmaf(meanv[k], wrow[k], acc);
        bf_out[img * 128 + t] = acc;
    }
}

// ---------------------------------------------------------------------------
// Kernel C: GRU step + head (unchanged).
// ---------------------------------------------------------------------------
__global__ __launch_bounds__(384) void gru_kernel(
    const float* __restrict__ hin,
    const int* __restrict__ atok, const int* __restrict__ uidx,
    const float* __restrict__ emb,
    const float* __restrict__ w_ih, const float* __restrict__ w_hh,
    const float* __restrict__ b_ih, const float* __restrict__ b_hh,
    const float* __restrict__ head_w, const float* __restrict__ head_b,
    float* __restrict__ out)
{
    const int img0 = blockIdx.x * 8;
    const int t = threadIdx.x;
    __shared__ float xin_s[8][168];
    __shared__ float h0_s[8][128];
    __shared__ float gis[8][384];
    __shared__ float ghs[8][384];
    __shared__ float hn_s[8][128];
    const float* bf = out + BATCH * 6;

    for (int idx = t; idx < 8 * 168; idx += 384) {
        const int r = idx / 168, k = idx - r * 168;
        const int row = img0 + r;
        float v;
        if (k < 128)      v = bf[row * 128 + k];
        else if (k < 136) v = (float)((atok[row] >> (k - 128)) & 1);
        else              v = emb[uidx[row] * 32 + (k - 136)];
        xin_s[r][k] = v;
    }
    for (int idx = t; idx < 8 * 128; idx += 384) {
        const int r = idx >> 7, k = idx & 127;
        h0_s[r][k] = hin[(img0 + r) * 128 + k];
    }
    __syncthreads();

    {
        const int o = t;
        float gi[8], gh[8];
        const float bi = b_ih[o], bh = b_hh[o];
#pragma unroll
        for (int r = 0; r < 8; ++r) { gi[r] = bi; gh[r] = bh; }
        const float* wi = w_ih + o * 168;
        const float* wh = w_hh + o * 128;
        for (int k = 0; k < 128; ++k) {
            const float wv = wi[k];
            const float wvh = wh[k];
#pragma unroll
            for (int r = 0; r < 8; ++r) {
                gi[r] = fmaf(wv, xin_s[r][k], gi[r]);
                gh[r] = fmaf(wvh, h0_s[r][k], gh[r]);
            }
        }
        for (int k = 128; k < 168; ++k) {
            const float wv = wi[k];
#pragma unroll
            for (int r = 0; r < 8; ++r) gi[r] = fmaf(wv, xin_s[r][k], gi[r]);
        }
#pragma unroll
        for (int r = 0; r < 8; ++r) { gis[r][o] = gi[r]; ghs[r][o] = gh[r]; }
    }
    __syncthreads();

    if (t < 128) {
#pragma unroll
        for (int r = 0; r < 8; ++r) {
            const float rg = 1.f / (1.f + expf(-(gis[r][t] + ghs[r][t])));
            const float z  = 1.f / (1.f + expf(-(gis[r][128 + t] + ghs[r][128 + t])));
            const float nn = tanhf(gis[r][256 + t] + rg * ghs[r][256 + t]);
            const float hn = (1.f - z) * nn + z * h0_s[r][t];
            hn_s[r][t] = hn;
            out[BATCH * 6 + (img0 + r) * 128 + t] = hn;
        }
    }
    __syncthreads();

    if (t < 48) {
        const int r = t / 6, j = t - r * 6;
        float acc = head_b[j];
        const float* wrow = head_w + j * 128;
        for (int k = 0; k < 128; ++k) acc = fmaf(hn_s[r][k], wrow[k], acc);
        out[(img0 + r) * 6 + j] = acc;
    }
}

extern "C" void kernel_launch(void* const* d_in, const int* in_sizes, int n_in,
                              void* d_out, int out_size, void* d_ws, size_t ws_size,
                              hipStream_t stream) {
    const float* board = (const float*)d_in[0];
    const float* h     = (const float*)d_in[1];
    const int*   atok  = (const int*)d_in[2];
    const int*   uidx  = (const int*)d_in[3];
    const float* w1 = (const float*)d_in[4];
    const float* b1 = (const float*)d_in[5];
    const float* w2 = (const float*)d_in[6];
    const float* b2 = (const float*)d_in[7];
    const float* w3 = (const float*)d_in[8];
    const float* b3 = (const float*)d_in[9];
    const float* w4 = (const float*)d_in[10];
    const float* b4 = (const float*)d_in[11];
    const float* pw = (const float*)d_in[12];
    const float* pb = (const float*)d_in[13];
    const float* emb  = (const float*)d_in[14];
    const float* w_ih = (const float*)d_in[15];
    const float* w_hh = (const float*)d_in[16];
    const float* b_ih = (const float*)d_in[17];
    const float* b_hh = (const float*)d_in[18];
    const float* head_w = (const float*)d_in[19];
    const float* head_b = (const float*)d_in[20];
    float* out = (float*)d_out;

    __hip_bfloat16* a2g = (__hip_bfloat16*)d_ws;
    __hip_bfloat16* wb = (__hip_bfloat16*)((char*)d_ws + A2G_BYTES);
    float* bf = out + BATCH * 6;

    prepack_weights<<<(WB_TOTAL + 255) / 256, 256, 0, stream>>>(w1, w2, w3, w4, wb);
    cnn12_kernel<<<BATCH, 256, 0, stream>>>(board, b1, b2, wb, a2g);
    cnn34_kernel<<<BATCH, 256, 0, stream>>>(a2g, b3, b4, pw, pb, wb, bf);
    gru_kernel<<<BATCH / 8, 384, 0, stream>>>(h, atok, uidx, emb, w_ih, w_hh,
                                              b_ih, b_hh, head_w, head_b, out);
}